// Round 4
// baseline (1336.429 us; speedup 1.0000x reference)
//
#include <hip/hip_runtime.h>

#define BATCH 2
#define NPTS  16384
#define BN    (BATCH * NPTS)
#define DIN   64
#define DM    128
#define NM    16

// ---------------------------------------------------------------------------
// Kernel 1: per-point projections.
//   f  = feature @ fc1_w + fc1_b
//   q  = f @ wq ; kf = f @ wk ; vf = f @ wv        (gather commutes with linear)
//   out = feature @ sc_w + sc_b                    (shortcut, written to d_out)
// ---------------------------------------------------------------------------
__global__ __launch_bounds__(256) void k_proj(
    const float* __restrict__ feat,
    const float* __restrict__ fc1_w, const float* __restrict__ fc1_b,
    const float* __restrict__ wq, const float* __restrict__ wk, const float* __restrict__ wv,
    const float* __restrict__ sc_w, const float* __restrict__ sc_b,
    float* __restrict__ qo, float* __restrict__ kfo, float* __restrict__ vfo,
    float* __restrict__ outp)
{
    __shared__ __align__(16) float featb[64][DIN];  // 16 KB
    __shared__ __align__(16) float fbuf[64][DM];    // 32 KB
    const int tid = threadIdx.x;
    const int p0  = blockIdx.x * 64;

    #pragma unroll
    for (int k = 0; k < 4; ++k) {
        int i4 = tid + k * 256;
        ((float4*)featb)[i4] = ((const float4*)(feat + (size_t)p0 * DIN))[i4];
    }
    __syncthreads();

    const int j    = tid & 127;
    const int base = (tid >> 7) * 32;
    float acc[32];

    #pragma unroll
    for (int pp = 0; pp < 32; ++pp) acc[pp] = fc1_b[j];
    for (int c = 0; c < DIN; c += 4) {
        float w0 = fc1_w[(c + 0) * DM + j];
        float w1 = fc1_w[(c + 1) * DM + j];
        float w2 = fc1_w[(c + 2) * DM + j];
        float w3 = fc1_w[(c + 3) * DM + j];
        #pragma unroll
        for (int pp = 0; pp < 32; ++pp) {
            float4 a = *(const float4*)&featb[base + pp][c];
            acc[pp] += a.x * w0 + a.y * w1 + a.z * w2 + a.w * w3;
        }
    }
    #pragma unroll
    for (int pp = 0; pp < 32; ++pp) fbuf[base + pp][j] = acc[pp];
    __syncthreads();

    for (int pass = 0; pass < 3; ++pass) {
        const float* W = pass == 0 ? wq : (pass == 1 ? wk : wv);
        float*       O = pass == 0 ? qo : (pass == 1 ? kfo : vfo);
        #pragma unroll
        for (int pp = 0; pp < 32; ++pp) acc[pp] = 0.f;
        for (int c = 0; c < DM; c += 4) {
            float w0 = W[(c + 0) * DM + j];
            float w1 = W[(c + 1) * DM + j];
            float w2 = W[(c + 2) * DM + j];
            float w3 = W[(c + 3) * DM + j];
            #pragma unroll
            for (int pp = 0; pp < 32; ++pp) {
                float4 a = *(const float4*)&fbuf[base + pp][c];
                acc[pp] += a.x * w0 + a.y * w1 + a.z * w2 + a.w * w3;
            }
        }
        #pragma unroll
        for (int pp = 0; pp < 32; ++pp) O[(size_t)(p0 + base + pp) * DM + j] = acc[pp];
    }

    #pragma unroll
    for (int pp = 0; pp < 32; ++pp) acc[pp] = sc_b[j];
    for (int c = 0; c < DIN; c += 4) {
        float w0 = sc_w[(c + 0) * DM + j];
        float w1 = sc_w[(c + 1) * DM + j];
        float w2 = sc_w[(c + 2) * DM + j];
        float w3 = sc_w[(c + 3) * DM + j];
        #pragma unroll
        for (int pp = 0; pp < 32; ++pp) {
            float4 a = *(const float4*)&featb[base + pp][c];
            acc[pp] += a.x * w0 + a.y * w1 + a.z * w2 + a.w * w3;
        }
    }
    #pragma unroll
    for (int pp = 0; pp < 32; ++pp) outp[(size_t)(p0 + base + pp) * DM + j] = acc[pp];
}

// ---------------------------------------------------------------------------
// Kernel 2: per-(point, neighbor) MLPs + vector-attention softmax.
// 1 wave = 1 point; lane owns channels {l, l+64}; 16 neighbors simultaneous.
// Zero __syncthreads: abuf is per-wave private; weights streamed from global
// (L2-resident); gathers phase-ordered so only ONE 32-reg gather array is
// live at a time (round-3 spilled by holding kf+vf = 64 regs across mm B):
//   kf gathered early  -> dies right after mm B      (a = q - kf + pos)
//   vf gathered after mm B, fused +pos -> lives across mm C/D only
// abuf swizzle: logical float4 group g of row r stored at g ^ ((r>>1)&3)
// -> conflict-free b128 stores; reads are wave-uniform broadcasts.
// ---------------------------------------------------------------------------
#define ASW(r) (((r) >> 1) & 3)

#define FMA16(O, W) do { \
    O[0]  += a0.x * (W); O[1]  += a0.y * (W); O[2]  += a0.z * (W); O[3]  += a0.w * (W); \
    O[4]  += a1.x * (W); O[5]  += a1.y * (W); O[6]  += a1.z * (W); O[7]  += a1.w * (W); \
    O[8]  += a2.x * (W); O[9]  += a2.y * (W); O[10] += a2.z * (W); O[11] += a2.w * (W); \
    O[12] += a3.x * (W); O[13] += a3.y * (W); O[14] += a3.z * (W); O[15] += a3.w * (W); } while (0)

__device__ __forceinline__ void mm128g(
    const float* __restrict__ Wg,          // global 128x128 row-major weights (L2-hot)
    const float (* __restrict__ aw)[NM],   // this wave's abuf [128][16] (swizzled)
    float* __restrict__ o0, float* __restrict__ o1,
    int lane)
{
    #pragma unroll 1                       // real loop: scheduling barrier, bounds
    for (int c0 = 0; c0 < DM; c0 += 16) {  // register demand per iteration
        #pragma unroll
        for (int cc = 0; cc < 16; ++cc) {
            const int s = (cc >> 1) & 3;   // == ASW(c0+cc), c0 % 16 == 0
            const float w0 = Wg[(size_t)(c0 + cc) * DM + lane];
            const float w1 = Wg[(size_t)(c0 + cc) * DM + 64 + lane];
            const float4* ar = (const float4*)&aw[c0 + cc][0];
            const float4 a0 = ar[0 ^ s];
            const float4 a1 = ar[1 ^ s];
            const float4 a2 = ar[2 ^ s];
            const float4 a3 = ar[3 ^ s];
            FMA16(o0, w0);
            FMA16(o1, w1);
        }
    }
}

__global__ __launch_bounds__(256, 2) void k_attn(
    const float* __restrict__ xyz, const int* __restrict__ nidx,
    const float* __restrict__ qg, const float* __restrict__ kfg, const float* __restrict__ vfg,
    const float* __restrict__ dw1, const float* __restrict__ db1,
    const float* __restrict__ dw2, const float* __restrict__ db2,
    const float* __restrict__ gw1, const float* __restrict__ gb1,
    const float* __restrict__ gw2, const float* __restrict__ gb2,
    float* __restrict__ ao)
{
    __shared__ __align__(16) float abuf[4][DM][NM];  // 32 KB, per-wave private

    const int tid  = threadIdx.x;
    const int wave = tid >> 6;
    const int lane = tid & 63;
    const int p    = blockIdx.x * 4 + wave;          // global point row, 0..32767
    const int b    = p >> 14;                        // batch
    const int rowb = b * NPTS;

    // neighbor indices (wave-uniform broadcast loads)
    int jjv[NM];
    #pragma unroll
    for (int m = 0; m < NM; ++m) jjv[m] = nidx[(size_t)p * NM + m];

    // kf gather issued early; consumed right after mm B (~8k cycles later)
    float kv0[NM], kv1[NM];
    #pragma unroll
    for (int m = 0; m < NM; ++m) {
        size_t r = (size_t)(rowb + jjv[m]) * DM;
        kv0[m] = kfg[r + lane];
        kv1[m] = kfg[r + 64 + lane];
    }
    const float q0 = qg[(size_t)p * DM + lane];
    const float q1 = qg[(size_t)p * DM + 64 + lane];

    const int sw = ASW(lane);                        // same for rows lane, 64+lane
    float4* arow0 = (float4*)&abuf[wave][lane][0];
    float4* arow1 = (float4*)&abuf[wave][64 + lane][0];

    float o0[NM], o1[NM];

    // phase A: h1 = relu(raw @ dw1 + db1) -> abuf (per-lane broadcast xyz loads)
    {
        const float xc0 = xyz[(size_t)p * 3 + 0];
        const float xc1 = xyz[(size_t)p * 3 + 1];
        const float xc2 = xyz[(size_t)p * 3 + 2];
        const float wA0 = dw1[lane],          wB0 = dw1[64 + lane];
        const float wA1 = dw1[DM + lane],     wB1 = dw1[DM + 64 + lane];
        const float wA2 = dw1[2 * DM + lane], wB2 = dw1[2 * DM + 64 + lane];
        const float bA = db1[lane], bB = db1[64 + lane];
        #pragma unroll
        for (int m = 0; m < NM; ++m) {
            size_t xr = (size_t)(rowb + jjv[m]) * 3;
            float r0 = xc0 - xyz[xr + 0];
            float r1 = xc1 - xyz[xr + 1];
            float r2 = xc2 - xyz[xr + 2];
            o0[m] = fmaxf(bA + r0 * wA0 + r1 * wA1 + r2 * wA2, 0.f);
            o1[m] = fmaxf(bB + r0 * wB0 + r1 * wB1 + r2 * wB2, 0.f);
        }
        #pragma unroll
        for (int g = 0; g < 4; ++g) {
            arow0[g ^ sw] = make_float4(o0[4*g+0], o0[4*g+1], o0[4*g+2], o0[4*g+3]);
            arow1[g ^ sw] = make_float4(o1[4*g+0], o1[4*g+1], o1[4*g+2], o1[4*g+3]);
        }
    }

    // layer B: pos = h1 @ dw2 + db2
    {
        const float bA = db2[lane], bB = db2[64 + lane];
        #pragma unroll
        for (int m = 0; m < NM; ++m) { o0[m] = bA; o1[m] = bB; }
    }
    mm128g(dw2, abuf[wave], o0, o1, lane);

    // a = (q - kf[idx]) + pos -> abuf   (kv dies here)
    #pragma unroll
    for (int m = 0; m < NM; ++m) {
        kv0[m] = (q0 - kv0[m]) + o0[m];
        kv1[m] = (q1 - kv1[m]) + o1[m];
    }
    #pragma unroll
    for (int g = 0; g < 4; ++g) {
        arow0[g ^ sw] = make_float4(kv0[4*g+0], kv0[4*g+1], kv0[4*g+2], kv0[4*g+3]);
        arow1[g ^ sw] = make_float4(kv1[4*g+0], kv1[4*g+1], kv1[4*g+2], kv1[4*g+3]);
    }

    // vf gather (late) fused with +pos; vv lives across mm C/D only
    float vv0[NM], vv1[NM];
    #pragma unroll
    for (int m = 0; m < NM; ++m) {
        size_t r = (size_t)(rowb + jjv[m]) * DM;
        vv0[m] = vfg[r + lane] + o0[m];
        vv1[m] = vfg[r + 64 + lane] + o1[m];
    }

    // layer C: h2 = relu(a @ gw1 + gb1) -> abuf
    {
        const float bA = gb1[lane], bB = gb1[64 + lane];
        #pragma unroll
        for (int m = 0; m < NM; ++m) { o0[m] = bA; o1[m] = bB; }
    }
    mm128g(gw1, abuf[wave], o0, o1, lane);
    #pragma unroll
    for (int g = 0; g < 4; ++g) {
        arow0[g ^ sw] = make_float4(fmaxf(o0[4*g+0], 0.f), fmaxf(o0[4*g+1], 0.f),
                                    fmaxf(o0[4*g+2], 0.f), fmaxf(o0[4*g+3], 0.f));
        arow1[g ^ sw] = make_float4(fmaxf(o1[4*g+0], 0.f), fmaxf(o1[4*g+1], 0.f),
                                    fmaxf(o1[4*g+2], 0.f), fmaxf(o1[4*g+3], 0.f));
    }

    // layer D: s = (h2 @ gw2 + gb2) / sqrt(128)
    {
        const float bA = gb2[lane], bB = gb2[64 + lane];
        #pragma unroll
        for (int m = 0; m < NM; ++m) { o0[m] = bA; o1[m] = bB; }
    }
    mm128g(gw2, abuf[wave], o0, o1, lane);

    const float scale = 0.08838834764831845f;  // 1/sqrt(128)
    float mx0 = -1e30f, mx1 = -1e30f;
    #pragma unroll
    for (int m = 0; m < NM; ++m) {
        o0[m] *= scale; o1[m] *= scale;
        mx0 = fmaxf(mx0, o0[m]); mx1 = fmaxf(mx1, o1[m]);
    }
    float s0 = 0.f, s1 = 0.f, r0 = 0.f, r1 = 0.f;
    #pragma unroll
    for (int m = 0; m < NM; ++m) {
        float e0 = __expf(o0[m] - mx0);
        float e1 = __expf(o1[m] - mx1);
        s0 += e0; s1 += e1;
        r0 += e0 * vv0[m];
        r1 += e1 * vv1[m];
    }
    ao[(size_t)p * DM + lane]      = r0 / s0;
    ao[(size_t)p * DM + 64 + lane] = r1 / s1;
}

// ---------------------------------------------------------------------------
// Kernel 3: out += attn_out @ fc2_w + fc2_b   (shortcut already in d_out)
// ---------------------------------------------------------------------------
__global__ __launch_bounds__(256) void k_final(
    const float* __restrict__ aog,
    const float* __restrict__ fc2_w, const float* __restrict__ fc2_b,
    float* __restrict__ outp)
{
    __shared__ __align__(16) float ab[64][DM];  // 32 KB
    const int tid = threadIdx.x;
    const int p0  = blockIdx.x * 64;

    #pragma unroll
    for (int k = 0; k < 8; ++k) {
        int i4 = tid + k * 256;
        ((float4*)ab)[i4] = ((const float4*)(aog + (size_t)p0 * DM))[i4];
    }
    __syncthreads();

    const int j    = tid & 127;
    const int base = (tid >> 7) * 32;
    float acc[32];
    #pragma unroll
    for (int pp = 0; pp < 32; ++pp) acc[pp] = fc2_b[j];
    for (int c = 0; c < DM; c += 4) {
        float w0 = fc2_w[(c + 0) * DM + j];
        float w1 = fc2_w[(c + 1) * DM + j];
        float w2 = fc2_w[(c + 2) * DM + j];
        float w3 = fc2_w[(c + 3) * DM + j];
        #pragma unroll
        for (int pp = 0; pp < 32; ++pp) {
            float4 a = *(const float4*)&ab[base + pp][c];
            acc[pp] += a.x * w0 + a.y * w1 + a.z * w2 + a.w * w3;
        }
    }
    #pragma unroll
    for (int pp = 0; pp < 32; ++pp) {
        size_t o = (size_t)(p0 + base + pp) * DM + j;
        outp[o] += acc[pp];
    }
}

// ---------------------------------------------------------------------------
extern "C" void kernel_launch(void* const* d_in, const int* in_sizes, int n_in,
                              void* d_out, int out_size, void* d_ws, size_t ws_size,
                              hipStream_t stream)
{
    const float* xyz     = (const float*)d_in[0];
    const float* feature = (const float*)d_in[1];
    const int*   nidx    = (const int*)d_in[2];
    const float* dw1     = (const float*)d_in[3];
    const float* db1     = (const float*)d_in[4];
    const float* dw2     = (const float*)d_in[5];
    const float* db2     = (const float*)d_in[6];
    const float* fc1_w   = (const float*)d_in[7];
    const float* fc1_b   = (const float*)d_in[8];
    const float* wq      = (const float*)d_in[9];
    const float* wk      = (const float*)d_in[10];
    const float* wv      = (const float*)d_in[11];
    const float* gw1     = (const float*)d_in[12];
    const float* gb1     = (const float*)d_in[13];
    const float* gw2     = (const float*)d_in[14];
    const float* gb2     = (const float*)d_in[15];
    const float* fc2_w   = (const float*)d_in[16];
    const float* fc2_b   = (const float*)d_in[17];
    const float* sc_w    = (const float*)d_in[18];
    const float* sc_b    = (const float*)d_in[19];

    float* ws = (float*)d_ws;
    const size_t SZ = (size_t)BN * DM;   // 4,194,304 floats
    float* q  = ws;
    float* kf = ws + SZ;
    float* vf = ws + 2 * SZ;
    float* ao = q;                       // attn-out aliases q (each wave reads its
                                         // own q row before writing that row)
    float* out = (float*)d_out;

    k_proj<<<BN / 64, 256, 0, stream>>>(feature, fc1_w, fc1_b, wq, wk, wv,
                                        sc_w, sc_b, q, kf, vf, out);
    k_attn<<<BN / 4, 256, 0, stream>>>(xyz, nidx, q, kf, vf,
                                       dw1, db1, dw2, db2,
                                       gw1, gb1, gw2, gb2, ao);
    k_final<<<BN / 64, 256, 0, stream>>>(ao, fc2_w, fc2_b, out);
}

// Round 7
// 1025.805 us; speedup vs baseline: 1.3028x; 1.3028x over previous
//
#include <hip/hip_runtime.h>

#define BATCH 2
#define NPTS  16384
#define BN    (BATCH * NPTS)
#define DIN   64
#define DM    128
#define NM    16

// ---------------------------------------------------------------------------
// Kernel 1: per-point projections.
//   f  = feature @ fc1_w + fc1_b
//   q  = f @ wq ; kf = f @ wk ; vf = f @ wv        (gather commutes with linear)
//   out = feature @ sc_w + sc_b                    (shortcut, written to d_out)
// ---------------------------------------------------------------------------
__global__ __launch_bounds__(256) void k_proj(
    const float* __restrict__ feat,
    const float* __restrict__ fc1_w, const float* __restrict__ fc1_b,
    const float* __restrict__ wq, const float* __restrict__ wk, const float* __restrict__ wv,
    const float* __restrict__ sc_w, const float* __restrict__ sc_b,
    float* __restrict__ qo, float* __restrict__ kfo, float* __restrict__ vfo,
    float* __restrict__ outp)
{
    __shared__ __align__(16) float featb[64][DIN];  // 16 KB
    __shared__ __align__(16) float fbuf[64][DM];    // 32 KB
    const int tid = threadIdx.x;
    const int p0  = blockIdx.x * 64;

    #pragma unroll
    for (int k = 0; k < 4; ++k) {
        int i4 = tid + k * 256;
        ((float4*)featb)[i4] = ((const float4*)(feat + (size_t)p0 * DIN))[i4];
    }
    __syncthreads();

    const int j    = tid & 127;
    const int base = (tid >> 7) * 32;
    float acc[32];

    #pragma unroll
    for (int pp = 0; pp < 32; ++pp) acc[pp] = fc1_b[j];
    for (int c = 0; c < DIN; c += 4) {
        float w0 = fc1_w[(c + 0) * DM + j];
        float w1 = fc1_w[(c + 1) * DM + j];
        float w2 = fc1_w[(c + 2) * DM + j];
        float w3 = fc1_w[(c + 3) * DM + j];
        #pragma unroll
        for (int pp = 0; pp < 32; ++pp) {
            float4 a = *(const float4*)&featb[base + pp][c];
            acc[pp] += a.x * w0 + a.y * w1 + a.z * w2 + a.w * w3;
        }
    }
    #pragma unroll
    for (int pp = 0; pp < 32; ++pp) fbuf[base + pp][j] = acc[pp];
    __syncthreads();

    for (int pass = 0; pass < 3; ++pass) {
        const float* W = pass == 0 ? wq : (pass == 1 ? wk : wv);
        float*       O = pass == 0 ? qo : (pass == 1 ? kfo : vfo);
        #pragma unroll
        for (int pp = 0; pp < 32; ++pp) acc[pp] = 0.f;
        for (int c = 0; c < DM; c += 4) {
            float w0 = W[(c + 0) * DM + j];
            float w1 = W[(c + 1) * DM + j];
            float w2 = W[(c + 2) * DM + j];
            float w3 = W[(c + 3) * DM + j];
            #pragma unroll
            for (int pp = 0; pp < 32; ++pp) {
                float4 a = *(const float4*)&fbuf[base + pp][c];
                acc[pp] += a.x * w0 + a.y * w1 + a.z * w2 + a.w * w3;
            }
        }
        #pragma unroll
        for (int pp = 0; pp < 32; ++pp) O[(size_t)(p0 + base + pp) * DM + j] = acc[pp];
    }

    #pragma unroll
    for (int pp = 0; pp < 32; ++pp) acc[pp] = sc_b[j];
    for (int c = 0; c < DIN; c += 4) {
        float w0 = sc_w[(c + 0) * DM + j];
        float w1 = sc_w[(c + 1) * DM + j];
        float w2 = sc_w[(c + 2) * DM + j];
        float w3 = sc_w[(c + 3) * DM + j];
        #pragma unroll
        for (int pp = 0; pp < 32; ++pp) {
            float4 a = *(const float4*)&featb[base + pp][c];
            acc[pp] += a.x * w0 + a.y * w1 + a.z * w2 + a.w * w3;
        }
    }
    #pragma unroll
    for (int pp = 0; pp < 32; ++pp) outp[(size_t)(p0 + base + pp) * DM + j] = acc[pp];
}

// ---------------------------------------------------------------------------
// Kernel 2: per-(point, neighbor) MLPs + vector-attention softmax.
// 1 wave = 1 point; lane owns channels {l, l+64}; 16 neighbors simultaneous.
// One __syncthreads (idxs visibility); weights streamed from global (L2-hot).
// SPILL FIX (rounds 3/4 spilled 550 MB to scratch): NO register array lives
// across an mm call. All gathered per-point state is staged in per-wave LDS:
//   - idxs[16]: neighbor indices (256 B; wave-uniform broadcast reads)
//   - obuf: kf gathered at start -> read back after mm B (a = q-kf+pos);
//           each thread reads only addresses it wrote (same-thread ordering).
//           Then overwritten with v+pos -> read only in the epilogue.
// Register live set across mms: o0/o1(32) + q(2) + bases ~= 60.
// abuf swizzle: logical float4 group g of row r stored at g ^ ((r>>1)&3)
// -> conflict-free b128 stores; mm reads are wave-uniform broadcasts
// (cross-lane write->read on the same LDS object: compiler inserts the
// lgkmcnt wait via may-alias ordering; validated on HW in rounds 3/4).
// obuf accesses are [m][lane] / [m][64+lane]: stride-1, conflict-free.
// ---------------------------------------------------------------------------
#define ASW(r) (((r) >> 1) & 3)

#define FMA16(O, W) do { \
    O[0]  += a0.x * (W); O[1]  += a0.y * (W); O[2]  += a0.z * (W); O[3]  += a0.w * (W); \
    O[4]  += a1.x * (W); O[5]  += a1.y * (W); O[6]  += a1.z * (W); O[7]  += a1.w * (W); \
    O[8]  += a2.x * (W); O[9]  += a2.y * (W); O[10] += a2.z * (W); O[11] += a2.w * (W); \
    O[12] += a3.x * (W); O[13] += a3.y * (W); O[14] += a3.z * (W); O[15] += a3.w * (W); } while (0)

__device__ __forceinline__ void mm128g(
    const float* __restrict__ Wg,          // global 128x128 row-major weights (L2-hot)
    const float (* __restrict__ aw)[NM],   // this wave's abuf [128][16] (swizzled)
    float* __restrict__ o0, float* __restrict__ o1,
    int lane)
{
    #pragma unroll 1                       // real loop: bounds per-iteration regs
    for (int c0 = 0; c0 < DM; c0 += 16) {
        #pragma unroll
        for (int cc = 0; cc < 16; ++cc) {
            const int s = (cc >> 1) & 3;   // == ASW(c0+cc), c0 % 16 == 0
            const float w0 = Wg[(size_t)(c0 + cc) * DM + lane];
            const float w1 = Wg[(size_t)(c0 + cc) * DM + 64 + lane];
            const float4* ar = (const float4*)&aw[c0 + cc][0];
            const float4 a0 = ar[0 ^ s];
            const float4 a1 = ar[1 ^ s];
            const float4 a2 = ar[2 ^ s];
            const float4 a3 = ar[3 ^ s];
            FMA16(o0, w0);
            FMA16(o1, w1);
        }
    }
}

__global__ __launch_bounds__(256, 2) void k_attn(
    const float* __restrict__ xyz, const int* __restrict__ nidx,
    const float* __restrict__ qg, const float* __restrict__ kfg, const float* __restrict__ vfg,
    const float* __restrict__ dw1, const float* __restrict__ db1,
    const float* __restrict__ dw2, const float* __restrict__ db2,
    const float* __restrict__ gw1, const float* __restrict__ gb1,
    const float* __restrict__ gw2, const float* __restrict__ gb2,
    float* __restrict__ ao)
{
    __shared__ __align__(16) float abuf[4][DM][NM];  // 32 KB, per-wave matmul input
    __shared__ __align__(16) float obuf[4][NM][DM];  // 32 KB, per-wave kf / v+pos
    __shared__ int idxs[4][NM];                      // 256 B, neighbor indices

    const int tid  = threadIdx.x;
    const int wave = tid >> 6;
    const int lane = tid & 63;
    const int p    = blockIdx.x * 4 + wave;          // global point row, 0..32767
    const int b    = p >> 14;                        // batch
    const int rowb = b * NPTS;

    float (* __restrict__ ow)[DM] = obuf[wave];      // [16][128]
    int* __restrict__ iw = idxs[wave];

    // neighbor indices -> LDS (no register array; broadcast reads later)
    if (lane < NM) iw[lane] = nidx[(size_t)p * NM + lane];
    __syncthreads();                                 // idxs visible to all lanes

    // gather kf -> obuf (raw); consumed after mm B
    #pragma unroll
    for (int m = 0; m < NM; ++m) {
        size_t r = (size_t)(rowb + iw[m]) * DM;
        ow[m][lane]      = kfg[r + lane];
        ow[m][64 + lane] = kfg[r + 64 + lane];
    }
    const float q0 = qg[(size_t)p * DM + lane];
    const float q1 = qg[(size_t)p * DM + 64 + lane];

    const int sw = ASW(lane);                        // same for rows lane, 64+lane
    float4* arow0 = (float4*)&abuf[wave][lane][0];
    float4* arow1 = (float4*)&abuf[wave][64 + lane][0];

    float o0[NM], o1[NM];

    // phase A: h1 = relu(raw @ dw1 + db1) -> abuf (per-lane broadcast xyz loads)
    {
        const float xc0 = xyz[(size_t)p * 3 + 0];
        const float xc1 = xyz[(size_t)p * 3 + 1];
        const float xc2 = xyz[(size_t)p * 3 + 2];
        const float wA0 = dw1[lane],          wB0 = dw1[64 + lane];
        const float wA1 = dw1[DM + lane],     wB1 = dw1[DM + 64 + lane];
        const float wA2 = dw1[2 * DM + lane], wB2 = dw1[2 * DM + 64 + lane];
        const float bA = db1[lane], bB = db1[64 + lane];
        #pragma unroll
        for (int m = 0; m < NM; ++m) {
            size_t xr = (size_t)(rowb + iw[m]) * 3;
            float r0 = xc0 - xyz[xr + 0];
            float r1 = xc1 - xyz[xr + 1];
            float r2 = xc2 - xyz[xr + 2];
            o0[m] = fmaxf(bA + r0 * wA0 + r1 * wA1 + r2 * wA2, 0.f);
            o1[m] = fmaxf(bB + r0 * wB0 + r1 * wB1 + r2 * wB2, 0.f);
        }
        #pragma unroll
        for (int g = 0; g < 4; ++g) {
            arow0[g ^ sw] = make_float4(o0[4*g+0], o0[4*g+1], o0[4*g+2], o0[4*g+3]);
            arow1[g ^ sw] = make_float4(o1[4*g+0], o1[4*g+1], o1[4*g+2], o1[4*g+3]);
        }
    }

    // layer B: pos = h1 @ dw2 + db2
    {
        const float bA = db2[lane], bB = db2[64 + lane];
        #pragma unroll
        for (int m = 0; m < NM; ++m) { o0[m] = bA; o1[m] = bB; }
    }
    mm128g(dw2, abuf[wave], o0, o1, lane);

    // a = (q - kf) + pos -> abuf  (kf read back from obuf; short-lived temps)
    {
        float a0v[NM], a1v[NM];
        #pragma unroll
        for (int m = 0; m < NM; ++m) {
            a0v[m] = (q0 - ow[m][lane])      + o0[m];
            a1v[m] = (q1 - ow[m][64 + lane]) + o1[m];
        }
        #pragma unroll
        for (int g = 0; g < 4; ++g) {
            arow0[g ^ sw] = make_float4(a0v[4*g+0], a0v[4*g+1], a0v[4*g+2], a0v[4*g+3]);
            arow1[g ^ sw] = make_float4(a1v[4*g+0], a1v[4*g+1], a1v[4*g+2], a1v[4*g+3]);
        }
    }

    // vf gather fused with +pos -> obuf (reuse)
    #pragma unroll
    for (int m = 0; m < NM; ++m) {
        size_t r = (size_t)(rowb + iw[m]) * DM;
        ow[m][lane]      = vfg[r + lane]      + o0[m];
        ow[m][64 + lane] = vfg[r + 64 + lane] + o1[m];
    }

    // layer C: h2 = relu(a @ gw1 + gb1) -> abuf
    {
        const float bA = gb1[lane], bB = gb1[64 + lane];
        #pragma unroll
        for (int m = 0; m < NM; ++m) { o0[m] = bA; o1[m] = bB; }
    }
    mm128g(gw1, abuf[wave], o0, o1, lane);
    #pragma unroll
    for (int g = 0; g < 4; ++g) {
        arow0[g ^ sw] = make_float4(fmaxf(o0[4*g+0], 0.f), fmaxf(o0[4*g+1], 0.f),
                                    fmaxf(o0[4*g+2], 0.f), fmaxf(o0[4*g+3], 0.f));
        arow1[g ^ sw] = make_float4(fmaxf(o1[4*g+0], 0.f), fmaxf(o1[4*g+1], 0.f),
                                    fmaxf(o1[4*g+2], 0.f), fmaxf(o1[4*g+3], 0.f));
    }

    // layer D: s = (h2 @ gw2 + gb2) / sqrt(128)
    {
        const float bA = gb2[lane], bB = gb2[64 + lane];
        #pragma unroll
        for (int m = 0; m < NM; ++m) { o0[m] = bA; o1[m] = bB; }
    }
    mm128g(gw2, abuf[wave], o0, o1, lane);

    const float scale = 0.08838834764831845f;  // 1/sqrt(128)
    float mx0 = -1e30f, mx1 = -1e30f;
    #pragma unroll
    for (int m = 0; m < NM; ++m) {
        o0[m] *= scale; o1[m] *= scale;
        mx0 = fmaxf(mx0, o0[m]); mx1 = fmaxf(mx1, o1[m]);
    }
    float s0 = 0.f, s1 = 0.f, r0 = 0.f, r1 = 0.f;
    #pragma unroll
    for (int m = 0; m < NM; ++m) {
        float e0 = __expf(o0[m] - mx0);
        float e1 = __expf(o1[m] - mx1);
        s0 += e0; s1 += e1;
        r0 += e0 * ow[m][lane];
        r1 += e1 * ow[m][64 + lane];
    }
    ao[(size_t)p * DM + lane]      = r0 / s0;
    ao[(size_t)p * DM + 64 + lane] = r1 / s1;
}

// ---------------------------------------------------------------------------
// Kernel 3: out += attn_out @ fc2_w + fc2_b   (shortcut already in d_out)
// ---------------------------------------------------------------------------
__global__ __launch_bounds__(256) void k_final(
    const float* __restrict__ aog,
    const float* __restrict__ fc2_w, const float* __restrict__ fc2_b,
    float* __restrict__ outp)
{
    __shared__ __align__(16) float ab[64][DM];  // 32 KB
    const int tid = threadIdx.x;
    const int p0  = blockIdx.x * 64;

    #pragma unroll
    for (int k = 0; k < 8; ++k) {
        int i4 = tid + k * 256;
        ((float4*)ab)[i4] = ((const float4*)(aog + (size_t)p0 * DM))[i4];
    }
    __syncthreads();

    const int j    = tid & 127;
    const int base = (tid >> 7) * 32;
    float acc[32];
    #pragma unroll
    for (int pp = 0; pp < 32; ++pp) acc[pp] = fc2_b[j];
    for (int c = 0; c < DM; c += 4) {
        float w0 = fc2_w[(c + 0) * DM + j];
        float w1 = fc2_w[(c + 1) * DM + j];
        float w2 = fc2_w[(c + 2) * DM + j];
        float w3 = fc2_w[(c + 3) * DM + j];
        #pragma unroll
        for (int pp = 0; pp < 32; ++pp) {
            float4 a = *(const float4*)&ab[base + pp][c];
            acc[pp] += a.x * w0 + a.y * w1 + a.z * w2 + a.w * w3;
        }
    }
    #pragma unroll
    for (int pp = 0; pp < 32; ++pp) {
        size_t o = (size_t)(p0 + base + pp) * DM + j;
        outp[o] += acc[pp];
    }
}

// ---------------------------------------------------------------------------
extern "C" void kernel_launch(void* const* d_in, const int* in_sizes, int n_in,
                              void* d_out, int out_size, void* d_ws, size_t ws_size,
                              hipStream_t stream)
{
    const float* xyz     = (const float*)d_in[0];
    const float* feature = (const float*)d_in[1];
    const int*   nidx    = (const int*)d_in[2];
    const float* dw1     = (const float*)d_in[3];
    const float* db1     = (const float*)d_in[4];
    const float* dw2     = (const float*)d_in[5];
    const float* db2     = (const float*)d_in[6];
    const float* fc1_w   = (const float*)d_in[7];
    const float* fc1_b   = (const float*)d_in[8];
    const float* wq      = (const float*)d_in[9];
    const float* wk      = (const float*)d_in[10];
    const float* wv      = (const float*)d_in[11];
    const float* gw1     = (const float*)d_in[12];
    const float* gb1     = (const float*)d_in[13];
    const float* gw2     = (const float*)d_in[14];
    const float* gb2     = (const float*)d_in[15];
    const float* fc2_w   = (const float*)d_in[16];
    const float* fc2_b   = (const float*)d_in[17];
    const float* sc_w    = (const float*)d_in[18];
    const float* sc_b    = (const float*)d_in[19];

    float* ws = (float*)d_ws;
    const size_t SZ = (size_t)BN * DM;   // 4,194,304 floats
    float* q  = ws;
    float* kf = ws + SZ;
    float* vf = ws + 2 * SZ;
    float* ao = q;                       // attn-out aliases q (each wave reads its
                                         // own q row before writing that row)
    float* out = (float*)d_out;

    k_proj<<<BN / 64, 256, 0, stream>>>(feature, fc1_w, fc1_b, wq, wk, wv,
                                        sc_w, sc_b, q, kf, vf, out);
    k_attn<<<BN / 4, 256, 0, stream>>>(xyz, nidx, q, kf, vf,
                                       dw1, db1, dw2, db2,
                                       gw1, gb1, gw2, gb2, ao);
    k_final<<<BN / 64, 256, 0, stream>>>(ao, fc2_w, fc2_b, out);
}